// Round 3
// baseline (130.414 us; speedup 1.0000x reference)
//
#include <hip/hip_runtime.h>
#include <hip/hip_bf16.h>
#include <float.h>

// RandomAugment: out = concat(p, where(dist(s, p) > 1, s, 0))
//   s = u * (max(p) - min(p)) + min(p)
//   dist[m] = sqrt(clip(min_n ||s_m - p_n||^2, 0))  via  s2 + pn2 - 2 s.p
//
// Inner loop: 3-fma chain + fmin = 4 VALU ops/pair (min_n fl(s2+x) == fl(s2+min_n x)).
// R2: (a) force VECTOR loads — the wave-uniform P4[n] address was scalarized to
// s_load (VGPR=24/36 evidence), whose out-of-order returns force lgkmcnt(0)
// serialization (~280 cy/point == the measured 120us). An opaque v_mov zero in
// the address defeats uniformity analysis; vmcnt is in-order so the B=4
// ping-pong pipeline becomes real. (b) CHUNKS 8->16: 1024-thr blocks, 512
// blocks = 32 waves/CU (was 16); launch_bounds(1024,8) caps VGPR<=64.

constexpr int CHUNKS = 16;  // waves per block, each handles N/CHUNKS points
constexpr int B = 4;        // prefetch batch (float4s in flight per wave)

__global__ __launch_bounds__(256) void prep_kernel(
    const float* __restrict__ p, int N,
    float* __restrict__ out, float4* __restrict__ P4, float* __restrict__ mmx) {
  const int tid = threadIdx.x;
  if (blockIdx.x == 0) {
    float mn0 = FLT_MAX, mn1 = FLT_MAX, mn2 = FLT_MAX;
    float mx0 = -FLT_MAX, mx1 = -FLT_MAX, mx2 = -FLT_MAX;
    for (int j = tid; j < N; j += 256) {
      float x = p[3 * j], y = p[3 * j + 1], z = p[3 * j + 2];
      mn0 = fminf(mn0, x); mx0 = fmaxf(mx0, x);
      mn1 = fminf(mn1, y); mx1 = fmaxf(mx1, y);
      mn2 = fminf(mn2, z); mx2 = fmaxf(mx2, z);
    }
    for (int off = 32; off; off >>= 1) {
      mn0 = fminf(mn0, __shfl_xor(mn0, off));
      mn1 = fminf(mn1, __shfl_xor(mn1, off));
      mn2 = fminf(mn2, __shfl_xor(mn2, off));
      mx0 = fmaxf(mx0, __shfl_xor(mx0, off));
      mx1 = fmaxf(mx1, __shfl_xor(mx1, off));
      mx2 = fmaxf(mx2, __shfl_xor(mx2, off));
    }
    __shared__ float smn[4][3], smx[4][3];
    const int w = tid >> 6;
    if ((tid & 63) == 0) {
      smn[w][0] = mn0; smn[w][1] = mn1; smn[w][2] = mn2;
      smx[w][0] = mx0; smx[w][1] = mx1; smx[w][2] = mx2;
    }
    __syncthreads();
    if (tid == 0) {
      for (int k = 0; k < 3; ++k) {
        float a = smn[0][k], b = smx[0][k];
        for (int w2 = 1; w2 < 4; ++w2) {
          a = fminf(a, smn[w2][k]);
          b = fmaxf(b, smx[w2][k]);
        }
        mmx[k] = a;       // mm
        mmx[3 + k] = b;   // mx
      }
    }
  } else {
    const int stride = (gridDim.x - 1) * 256;
    for (int j = (blockIdx.x - 1) * 256 + tid; j < N; j += stride) {
      float x = p[3 * j], y = p[3 * j + 1], z = p[3 * j + 2];
      out[3 * j] = x; out[3 * j + 1] = y; out[3 * j + 2] = z;
      float n2 = __fadd_rn(__fadd_rn(__fmul_rn(x, x), __fmul_rn(y, y)),
                           __fmul_rn(z, z));
      P4[j] = make_float4(x, y, z, n2);
    }
  }
}

__global__ __launch_bounds__(64 * CHUNKS, 8) void dist_kernel(
    const float* __restrict__ u, int M, int N,
    const float4* __restrict__ P4, const float* __restrict__ mmx,
    float* __restrict__ out) {
  const int lane = threadIdx.x;        // 0..63  -> sample within block
  const int wv = threadIdx.y;          // 0..CHUNKS-1 -> point chunk
  const int samp = blockIdx.x * 64 + lane;

  const float mm0 = mmx[0], mm1 = mmx[1], mm2 = mmx[2];
  const float r0 = __fsub_rn(mmx[3], mm0);
  const float r1 = __fsub_rn(mmx[4], mm1);
  const float r2 = __fsub_rn(mmx[5], mm2);

  float sx = 0.0f, sy = 0.0f, sz = 0.0f;
  if (samp < M) {
    // bit-exact with numpy's u*(mx-mm)+mm (mul then add, no contraction)
    sx = __fadd_rn(__fmul_rn(u[3 * samp], r0), mm0);
    sy = __fadd_rn(__fmul_rn(u[3 * samp + 1], r1), mm1);
    sz = __fadd_rn(__fmul_rn(u[3 * samp + 2], r2), mm2);
  }
  const float m2x = -2.0f * sx, m2y = -2.0f * sy, m2z = -2.0f * sz;

  // Opaque zero in a VGPR: uniformity analysis must treat the address as
  // divergent -> global_load_dwordx4 (vmcnt, in-order) instead of s_load
  // (lgkmcnt, out-of-order, serializing).
  int vz;
  asm volatile("v_mov_b32 %0, 0" : "=v"(vz));

  const int ccnt = (N + CHUNKS - 1) / CHUNKS;
  const int beg = wv * ccnt;
  const int end = min(beg + ccnt, N);
  const int cnt = end - beg;
  const float4* __restrict__ base = P4 + beg + vz;

  float dmin0 = FLT_MAX, dmin1 = FLT_MAX;

  if (cnt >= 2 * B) {
    // ping-pong double buffer: compute batch A while batch B loads, and v.v.
    float4 bufA[B], bufB[B];
#pragma unroll
    for (int b = 0; b < B; ++b) bufA[b] = base[b];
    int n = 0;
    for (; n + 2 * B <= cnt; n += 2 * B) {
#pragma unroll
      for (int b = 0; b < B; ++b) bufB[b] = base[n + B + b];
#pragma unroll
      for (int b = 0; b < B; ++b) {
        float4 q = bufA[b];
        float t = fmaf(m2x, q.x, fmaf(m2y, q.y, fmaf(m2z, q.z, q.w)));
        if (b & 1) dmin1 = fminf(dmin1, t); else dmin0 = fminf(dmin0, t);
      }
      // prefetch next A; on the final iteration re-read in-bounds data instead
      const int na = (n + 4 * B <= cnt) ? n + 2 * B : n;
#pragma unroll
      for (int b = 0; b < B; ++b) bufA[b] = base[na + b];
#pragma unroll
      for (int b = 0; b < B; ++b) {
        float4 q = bufB[b];
        float t = fmaf(m2x, q.x, fmaf(m2y, q.y, fmaf(m2z, q.z, q.w)));
        if (b & 1) dmin1 = fminf(dmin1, t); else dmin0 = fminf(dmin0, t);
      }
    }
    for (; n < cnt; ++n) {
      float4 q = base[n];
      float t = fmaf(m2x, q.x, fmaf(m2y, q.y, fmaf(m2z, q.z, q.w)));
      dmin0 = fminf(dmin0, t);
    }
  } else {
    for (int n = 0; n < cnt; ++n) {
      float4 q = base[n];
      float t = fmaf(m2x, q.x, fmaf(m2y, q.y, fmaf(m2z, q.z, q.w)));
      dmin0 = fminf(dmin0, t);
    }
  }
  float dmin = fminf(dmin0, dmin1);

  __shared__ float red[CHUNKS][64];
  red[wv][lane] = dmin;
  __syncthreads();

  if (wv == 0 && samp < M) {
    float d = red[0][lane];
#pragma unroll
    for (int w = 1; w < CHUNKS; ++w) d = fminf(d, red[w][lane]);
    const float s2 = __fadd_rn(
        __fadd_rn(__fmul_rn(sx, sx), __fmul_rn(sy, sy)), __fmul_rn(sz, sz));
    const float d2 = __fadd_rn(s2, d);
    const float dist = sqrtf(fmaxf(d2, 0.0f));
    const bool keep = dist > 1.0f;
    float* o = out + (size_t)(N + samp) * 3;
    o[0] = keep ? sx : 0.0f;
    o[1] = keep ? sy : 0.0f;
    o[2] = keep ? sz : 0.0f;
  }
}

extern "C" void kernel_launch(void* const* d_in, const int* in_sizes, int n_in,
                              void* d_out, int out_size, void* d_ws, size_t ws_size,
                              hipStream_t stream) {
  const float* p = (const float*)d_in[0];
  const float* u = (const float*)d_in[1];
  const int N = in_sizes[0] / 3;   // 8192
  const int M = in_sizes[1] / 3;   // 32768
  float* out = (float*)d_out;

  float* mmx = (float*)d_ws;                       // 6 floats
  float4* P4 = (float4*)((char*)d_ws + 256);       // N float4s

  const int copy_blocks = (N + 255) / 256;
  prep_kernel<<<dim3(1 + copy_blocks), 256, 0, stream>>>(p, N, out, P4, mmx);

  const int sblocks = (M + 63) / 64;
  dist_kernel<<<dim3(sblocks), dim3(64, CHUNKS), 0, stream>>>(u, M, N, P4, mmx, out);
}

// Round 4
// 46.749 us; speedup vs baseline: 2.7896x; 2.7896x over previous
//
#include <hip/hip_runtime.h>
#include <hip/hip_bf16.h>
#include <float.h>

// RandomAugment: out = concat(p, where(dist(s, p) > 1, s, 0))
//   dist[m]^2 = s2 + min_n (pn2 - 2 s.p_n)   (monotone rounding => exact)
//
// R3: lane=point, samples in SGPRs. R0-R2 all ran ~128us regardless of
// occupancy/structure because broadcasting one point to 64 lanes via a
// vector load costs ~16-19 cy/load of per-CU L1 return BW (64 lanes x 16B
// = 1KB per instr, 63/64 wasted). Now each load fetches 64 DISTINCT points
// (coalesced), samples are wave-uniform SGPR operands of v_fma (1 SGPR/instr
// is legal), per-CU load count drops 16x. Inner loop stays 4 VALU ops/pair.

constexpr int SPB = 32;    // samples per block
constexpr int WAVES = 4;   // waves per block, each owns a point chunk
constexpr int GRP = 16;    // samples per SGPR group
constexpr int NGRP = SPB / GRP;   // 2

__global__ __launch_bounds__(256) void prep_kernel(
    const float* __restrict__ p, int N,
    float* __restrict__ out, float4* __restrict__ P4, float* __restrict__ mmx) {
  const int tid = threadIdx.x;
  if (blockIdx.x == 0) {
    float mn0 = FLT_MAX, mn1 = FLT_MAX, mn2 = FLT_MAX;
    float mx0 = -FLT_MAX, mx1 = -FLT_MAX, mx2 = -FLT_MAX;
    for (int j = tid; j < N; j += 256) {
      float x = p[3 * j], y = p[3 * j + 1], z = p[3 * j + 2];
      mn0 = fminf(mn0, x); mx0 = fmaxf(mx0, x);
      mn1 = fminf(mn1, y); mx1 = fmaxf(mx1, y);
      mn2 = fminf(mn2, z); mx2 = fmaxf(mx2, z);
    }
    for (int off = 32; off; off >>= 1) {
      mn0 = fminf(mn0, __shfl_xor(mn0, off));
      mn1 = fminf(mn1, __shfl_xor(mn1, off));
      mn2 = fminf(mn2, __shfl_xor(mn2, off));
      mx0 = fmaxf(mx0, __shfl_xor(mx0, off));
      mx1 = fmaxf(mx1, __shfl_xor(mx1, off));
      mx2 = fmaxf(mx2, __shfl_xor(mx2, off));
    }
    __shared__ float smn[4][3], smx[4][3];
    const int w = tid >> 6;
    if ((tid & 63) == 0) {
      smn[w][0] = mn0; smn[w][1] = mn1; smn[w][2] = mn2;
      smx[w][0] = mx0; smx[w][1] = mx1; smx[w][2] = mx2;
    }
    __syncthreads();
    if (tid == 0) {
      for (int k = 0; k < 3; ++k) {
        float a = smn[0][k], b = smx[0][k];
        for (int w2 = 1; w2 < 4; ++w2) {
          a = fminf(a, smn[w2][k]);
          b = fmaxf(b, smx[w2][k]);
        }
        mmx[k] = a;       // mm
        mmx[3 + k] = b;   // mx
      }
    }
  } else {
    const int stride = (gridDim.x - 1) * 256;
    for (int j = (blockIdx.x - 1) * 256 + tid; j < N; j += stride) {
      float x = p[3 * j], y = p[3 * j + 1], z = p[3 * j + 2];
      out[3 * j] = x; out[3 * j + 1] = y; out[3 * j + 2] = z;
      float n2 = __fadd_rn(__fadd_rn(__fmul_rn(x, x), __fmul_rn(y, y)),
                           __fmul_rn(z, z));
      P4[j] = make_float4(x, y, z, n2);
    }
  }
}

__device__ __forceinline__ float rdlane(float v, int l) {
  return __int_as_float(__builtin_amdgcn_readlane(__float_as_int(v), l));
}

__global__ __launch_bounds__(64 * WAVES) void dist_kernel(
    const float* __restrict__ u, int M, int N,
    const float4* __restrict__ P4, const float* __restrict__ mmx,
    float* __restrict__ out) {
  const int lane = threadIdx.x & 63;
  const int wv = threadIdx.x >> 6;
  const int sbase = blockIdx.x * SPB;

  // ---- phase 1 (all waves, identical): per-lane sample coords ----
  const float mm0 = mmx[0], mm1 = mmx[1], mm2 = mmx[2];
  const float r0 = __fsub_rn(mmx[3], mm0);
  const float r1 = __fsub_rn(mmx[4], mm1);
  const float r2 = __fsub_rn(mmx[5], mm2);

  int sidx = min(sbase + (lane & (SPB - 1)), M - 1);
  // bit-exact with numpy's u*(mx-mm)+mm (mul then add, no contraction)
  const float sx = __fadd_rn(__fmul_rn(u[3 * sidx], r0), mm0);
  const float sy = __fadd_rn(__fmul_rn(u[3 * sidx + 1], r1), mm1);
  const float sz = __fadd_rn(__fmul_rn(u[3 * sidx + 2], r2), mm2);
  const float m2x = -2.0f * sx, m2y = -2.0f * sy, m2z = -2.0f * sz;
  const float s2 = __fadd_rn(
      __fadd_rn(__fmul_rn(sx, sx), __fmul_rn(sy, sy)), __fmul_rn(sz, sz));

  // ---- phase 2: this wave's point chunk vs all SPB samples ----
  const int chunk = (N + WAVES - 1) / WAVES;       // 2048
  const int cbeg = wv * chunk;
  const int iters = (chunk + 63) / 64;             // 32

  __shared__ float red[WAVES][64][20];   // per-wave transpose scratch (padded)
  __shared__ float part[WAVES][64];      // cross-wave partials

  float dred[NGRP];

#pragma unroll
  for (int g = 0; g < NGRP; ++g) {
    // 16 samples' -2*s coords into wave-uniform (SGPR) values
    float smx_[GRP], smy_[GRP], smz_[GRP];
#pragma unroll
    for (int s = 0; s < GRP; ++s) {
      smx_[s] = rdlane(m2x, g * GRP + s);
      smy_[s] = rdlane(m2y, g * GRP + s);
      smz_[s] = rdlane(m2z, g * GRP + s);
    }

    float dm[GRP];
#pragma unroll
    for (int s = 0; s < GRP; ++s) dm[s] = FLT_MAX;

    // ping-pong: load next 64 points while computing current
    float4 q = P4[min(cbeg + lane, N - 1)];
    for (int it = 0; it < iters; ++it) {
      float4 qn = q;
      if (it + 1 < iters) qn = P4[min(cbeg + (it + 1) * 64 + lane, N - 1)];
#pragma unroll
      for (int s = 0; s < GRP; ++s) {
        // t = pn2 - 2 s.p  (3 fma, each with exactly one wave-uniform operand)
        float t = fmaf(smx_[s], q.x,
                  fmaf(smy_[s], q.y,
                  fmaf(smz_[s], q.z, q.w)));
        dm[s] = fminf(dm[s], t);
      }
      q = qn;
    }

    // in-wave reduce: transpose via LDS then fold lanes
    __builtin_amdgcn_wave_barrier();
#pragma unroll
    for (int s = 0; s < GRP; s += 4)
      *(float4*)&red[wv][lane][s] =
          make_float4(dm[s], dm[s + 1], dm[s + 2], dm[s + 3]);
    __builtin_amdgcn_wave_barrier();
    const int ss = lane & 15, qq = lane >> 4;
    float pmin = FLT_MAX;
#pragma unroll
    for (int r = 0; r < 16; ++r)
      pmin = fminf(pmin, red[wv][qq * 16 + r][ss]);
    pmin = fminf(pmin, __shfl_xor(pmin, 16));
    pmin = fminf(pmin, __shfl_xor(pmin, 32));
    dred[g] = pmin;   // every lane: group-g chunk-min for sample (lane&15)
    __builtin_amdgcn_wave_barrier();
  }

  // lane l's own sample partial (l < SPB): group = l>>4, idx = l&15
  float val = (lane & 16) ? dred[1] : dred[0];
  part[wv][lane] = val;
  __syncthreads();

  // ---- finalize: combine the WAVES chunks, mask, store ----
  const int t = threadIdx.x;
  if (t < SPB && sbase + t < M) {
    float d = part[0][t];
#pragma unroll
    for (int w = 1; w < WAVES; ++w) d = fminf(d, part[w][t]);
    const float d2 = __fadd_rn(s2, d);   // wave0 lane t holds sample t's s2/sx/sy/sz
    const float dist = sqrtf(fmaxf(d2, 0.0f));
    const bool keep = dist > 1.0f;
    float* o = out + (size_t)(N + sbase + t) * 3;
    o[0] = keep ? sx : 0.0f;
    o[1] = keep ? sy : 0.0f;
    o[2] = keep ? sz : 0.0f;
  }
}

extern "C" void kernel_launch(void* const* d_in, const int* in_sizes, int n_in,
                              void* d_out, int out_size, void* d_ws, size_t ws_size,
                              hipStream_t stream) {
  const float* p = (const float*)d_in[0];
  const float* u = (const float*)d_in[1];
  const int N = in_sizes[0] / 3;   // 8192
  const int M = in_sizes[1] / 3;   // 32768
  float* out = (float*)d_out;

  float* mmx = (float*)d_ws;                       // 6 floats
  float4* P4 = (float4*)((char*)d_ws + 256);       // N float4s

  const int copy_blocks = (N + 255) / 256;
  prep_kernel<<<dim3(1 + copy_blocks), 256, 0, stream>>>(p, N, out, P4, mmx);

  const int sblocks = (M + SPB - 1) / SPB;
  dist_kernel<<<dim3(sblocks), dim3(64 * WAVES), 0, stream>>>(u, M, N, P4, mmx, out);
}

// Round 5
// 40.484 us; speedup vs baseline: 3.2213x; 1.1547x over previous
//
#include <hip/hip_runtime.h>
#include <hip/hip_bf16.h>
#include <float.h>

// RandomAugment: out = concat(p, where(dist(s, p) > 1, s, 0))
//   dist[m]^2 = s2 + min_n (pn2 - 2 s.p_n)   (monotone rounding => exact)
//
// R3 established: lane=point (coalesced), samples wave-uniform in SGPRs
// (1 SGPR operand per v_fma is legal), 4 VALU slots/pair.
// R5: single-scan per wave (SPB=16, NGRP=1), SALU base-increment addressing
// (uniform ptr + lane offset), 2-point unroll with fminf(fminf()) for
// v_min3_f32, grid 2048 blocks for ~7 LDS-limited blocks/CU occupancy.

constexpr int SPB = 16;    // samples per block (= one SGPR group)
constexpr int WAVES = 4;   // waves per block, each owns a point chunk
constexpr int GRP = 16;    // samples per SGPR group

__global__ __launch_bounds__(256) void prep_kernel(
    const float* __restrict__ p, int N,
    float* __restrict__ out, float4* __restrict__ P4, float* __restrict__ mmx) {
  const int tid = threadIdx.x;
  if (blockIdx.x == 0) {
    float mn0 = FLT_MAX, mn1 = FLT_MAX, mn2 = FLT_MAX;
    float mx0 = -FLT_MAX, mx1 = -FLT_MAX, mx2 = -FLT_MAX;
    for (int j = tid; j < N; j += 256) {
      float x = p[3 * j], y = p[3 * j + 1], z = p[3 * j + 2];
      mn0 = fminf(mn0, x); mx0 = fmaxf(mx0, x);
      mn1 = fminf(mn1, y); mx1 = fmaxf(mx1, y);
      mn2 = fminf(mn2, z); mx2 = fmaxf(mx2, z);
    }
    for (int off = 32; off; off >>= 1) {
      mn0 = fminf(mn0, __shfl_xor(mn0, off));
      mn1 = fminf(mn1, __shfl_xor(mn1, off));
      mn2 = fminf(mn2, __shfl_xor(mn2, off));
      mx0 = fmaxf(mx0, __shfl_xor(mx0, off));
      mx1 = fmaxf(mx1, __shfl_xor(mx1, off));
      mx2 = fmaxf(mx2, __shfl_xor(mx2, off));
    }
    __shared__ float smn[4][3], smx[4][3];
    const int w = tid >> 6;
    if ((tid & 63) == 0) {
      smn[w][0] = mn0; smn[w][1] = mn1; smn[w][2] = mn2;
      smx[w][0] = mx0; smx[w][1] = mx1; smx[w][2] = mx2;
    }
    __syncthreads();
    if (tid == 0) {
      for (int k = 0; k < 3; ++k) {
        float a = smn[0][k], b = smx[0][k];
        for (int w2 = 1; w2 < 4; ++w2) {
          a = fminf(a, smn[w2][k]);
          b = fmaxf(b, smx[w2][k]);
        }
        mmx[k] = a;       // mm
        mmx[3 + k] = b;   // mx
      }
    }
  } else {
    const int stride = (gridDim.x - 1) * 256;
    for (int j = (blockIdx.x - 1) * 256 + tid; j < N; j += stride) {
      float x = p[3 * j], y = p[3 * j + 1], z = p[3 * j + 2];
      out[3 * j] = x; out[3 * j + 1] = y; out[3 * j + 2] = z;
      float n2 = __fadd_rn(__fadd_rn(__fmul_rn(x, x), __fmul_rn(y, y)),
                           __fmul_rn(z, z));
      P4[j] = make_float4(x, y, z, n2);
    }
  }
}

__device__ __forceinline__ float rdlane(float v, int l) {
  return __int_as_float(__builtin_amdgcn_readlane(__float_as_int(v), l));
}

__global__ __launch_bounds__(64 * WAVES) void dist_kernel(
    const float* __restrict__ u, int M, int N,
    const float4* __restrict__ P4, const float* __restrict__ mmx,
    float* __restrict__ out) {
  const int lane = threadIdx.x & 63;
  const int wv = threadIdx.x >> 6;
  const int sbase = blockIdx.x * SPB;

  // ---- per-lane sample coords (16 samples replicated 4x across the wave) ----
  const float mm0 = mmx[0], mm1 = mmx[1], mm2 = mmx[2];
  const float r0 = __fsub_rn(mmx[3], mm0);
  const float r1 = __fsub_rn(mmx[4], mm1);
  const float r2 = __fsub_rn(mmx[5], mm2);

  int sidx = min(sbase + (lane & (SPB - 1)), M - 1);
  // bit-exact with numpy's u*(mx-mm)+mm (mul then add, no contraction)
  const float sx = __fadd_rn(__fmul_rn(u[3 * sidx], r0), mm0);
  const float sy = __fadd_rn(__fmul_rn(u[3 * sidx + 1], r1), mm1);
  const float sz = __fadd_rn(__fmul_rn(u[3 * sidx + 2], r2), mm2);
  const float m2x = -2.0f * sx, m2y = -2.0f * sy, m2z = -2.0f * sz;
  const float s2 = __fadd_rn(
      __fadd_rn(__fmul_rn(sx, sx), __fmul_rn(sy, sy)), __fmul_rn(sz, sz));

  // 16 samples' -2*s coords into wave-uniform (SGPR) values
  float smx_[GRP], smy_[GRP], smz_[GRP];
#pragma unroll
  for (int s = 0; s < GRP; ++s) {
    smx_[s] = rdlane(m2x, s);
    smy_[s] = rdlane(m2y, s);
    smz_[s] = rdlane(m2z, s);
  }

  // ---- this wave's point chunk vs the 16 samples ----
  const int chunk = (N + WAVES - 1) / WAVES;        // 2048 for N=8192
  const int cbeg = wv * chunk;
  const int avail = min(chunk, max(0, N - cbeg));   // points this wave owns

  float dm[GRP];
#pragma unroll
  for (int s = 0; s < GRP; ++s) dm[s] = FLT_MAX;

  const float4* __restrict__ ptr = P4 + cbeg;       // wave-uniform base
  const int pairs = avail >> 7;                     // 128-pt double-tiles

  if (pairs > 0) {
    float4 qA = ptr[lane];
    float4 qB = ptr[64 + lane];
    const float4* pf = ptr + 128;
#pragma unroll 2
    for (int i = 0; i < pairs; ++i) {
      const float4* nf = (i + 1 < pairs) ? pf : ptr;  // uniform select (SALU)
      float4 qC = nf[lane];
      float4 qD = nf[64 + lane];
      pf += 128;
#pragma unroll
      for (int s = 0; s < GRP; ++s) {
        // t = pn2 - 2 s.p  (3 fma, one wave-uniform SGPR operand each)
        float t0 = fmaf(smx_[s], qA.x,
                   fmaf(smy_[s], qA.y, fmaf(smz_[s], qA.z, qA.w)));
        float t1 = fmaf(smx_[s], qB.x,
                   fmaf(smy_[s], qB.y, fmaf(smz_[s], qB.z, qB.w)));
        dm[s] = fminf(dm[s], fminf(t0, t1));  // -> v_min3_f32
      }
      qA = qC; qB = qD;
    }
  }
  // tail: remaining [pairs*128, avail) points, clamped loads (duplicates of
  // real points are harmless under min)
  for (int j = pairs << 7; j < avail; j += 64) {
    float4 q = P4[min(cbeg + j + lane, N - 1)];
#pragma unroll
    for (int s = 0; s < GRP; ++s) {
      float t = fmaf(smx_[s], q.x,
                fmaf(smy_[s], q.y, fmaf(smz_[s], q.z, q.w)));
      dm[s] = fminf(dm[s], t);
    }
  }

  // ---- in-wave reduce: transpose via LDS then fold lanes ----
  __shared__ float red[WAVES][64][20];   // padded transpose scratch
  __shared__ float part[WAVES][64];      // cross-wave partials

  __builtin_amdgcn_wave_barrier();
#pragma unroll
  for (int s = 0; s < GRP; s += 4)
    *(float4*)&red[wv][lane][s] =
        make_float4(dm[s], dm[s + 1], dm[s + 2], dm[s + 3]);
  __builtin_amdgcn_wave_barrier();
  const int ss = lane & 15, qq = lane >> 4;
  float pmin = FLT_MAX;
#pragma unroll
  for (int r = 0; r < 16; ++r)
    pmin = fminf(pmin, red[wv][qq * 16 + r][ss]);
  pmin = fminf(pmin, __shfl_xor(pmin, 16));
  pmin = fminf(pmin, __shfl_xor(pmin, 32));
  __builtin_amdgcn_wave_barrier();

  part[wv][lane] = pmin;   // lane l holds chunk-min for sample (l & 15)
  __syncthreads();

  // ---- finalize: combine the WAVES chunks, mask, store ----
  const int t = threadIdx.x;
  if (t < SPB && sbase + t < M) {
    float d = part[0][t];
#pragma unroll
    for (int w = 1; w < WAVES; ++w) d = fminf(d, part[w][t]);
    const float d2 = __fadd_rn(s2, d);   // wave0 lane t holds sample t's s2/sx/sy/sz
    const float dist = sqrtf(fmaxf(d2, 0.0f));
    const bool keep = dist > 1.0f;
    float* o = out + (size_t)(N + sbase + t) * 3;
    o[0] = keep ? sx : 0.0f;
    o[1] = keep ? sy : 0.0f;
    o[2] = keep ? sz : 0.0f;
  }
}

extern "C" void kernel_launch(void* const* d_in, const int* in_sizes, int n_in,
                              void* d_out, int out_size, void* d_ws, size_t ws_size,
                              hipStream_t stream) {
  const float* p = (const float*)d_in[0];
  const float* u = (const float*)d_in[1];
  const int N = in_sizes[0] / 3;   // 8192
  const int M = in_sizes[1] / 3;   // 32768
  float* out = (float*)d_out;

  float* mmx = (float*)d_ws;                       // 6 floats
  float4* P4 = (float4*)((char*)d_ws + 256);       // N float4s

  const int copy_blocks = (N + 255) / 256;
  prep_kernel<<<dim3(1 + copy_blocks), 256, 0, stream>>>(p, N, out, P4, mmx);

  const int sblocks = (M + SPB - 1) / SPB;
  dist_kernel<<<dim3(sblocks), dim3(64 * WAVES), 0, stream>>>(u, M, N, P4, mmx, out);
}